// Round 2
// baseline (5178.523 us; speedup 1.0000x reference)
//
#include <hip/hip_runtime.h>
#include <stdint.h>
#include <math.h>

typedef unsigned short u16;

#define NHEADS 12
#define NTOK 49
#define CDIM 384
#define HIDDIM 1536
#define HDIM 32
#define BNWIN 2048                 // 32 batches * 64 windows
#define MROWS 100352               // BNWIN * NTOK
#define QKV_STRIDE ((size_t)BNWIN * NHEADS * NTOK * HDIM)   // 38535168 elems
#define ATT_SCALE 0.17677669529663687f

__device__ __forceinline__ float bf2f(u16 u) {
    union { unsigned int i; float f; } z; z.i = ((unsigned int)u) << 16; return z.f;
}
__device__ __forceinline__ u16 f2bf(float f) {
    union { float f; unsigned int i; } z; z.f = f;
    unsigned int i = z.i;
    i += 0x7FFFu + ((i >> 16) & 1u);   // round-to-nearest-even
    return (u16)(i >> 16);
}

// ---------------- LN1 + roll(-3,-3) + window partition (gather) ----------------
// one wave per output window-token row; writes A[t][c] (bf16) in window order
__global__ __launch_bounds__(256) void k_ln1(const float* __restrict__ x,
    const float* __restrict__ g, const float* __restrict__ b, u16* __restrict__ outw)
{
    const int lane = threadIdx.x & 63;
    const int t = blockIdx.x * 4 + (threadIdx.x >> 6);     // 0..100351
    const int wi = t / NTOK, n = t % NTOK;
    const int bb = wi >> 6, w64 = wi & 63;
    const int p = (w64 >> 3) * 7 + n / 7;
    const int q = (w64 & 7) * 7 + n % 7;
    const int sh = (p + 3) % 56, sw = (q + 3) % 56;        // roll by -3: win[p] = x[(p+3)%56]
    const float* row = x + ((size_t)bb * 3136 + sh * 56 + sw) * CDIM;
    float v[6]; float s = 0.f, sq = 0.f;
#pragma unroll
    for (int i = 0; i < 6; i++) {
        v[i] = row[lane + 64 * i];
        s += v[i]; sq += v[i] * v[i];
    }
#pragma unroll
    for (int off = 32; off >= 1; off >>= 1) {
        s  += __shfl_xor(s, off, 64);
        sq += __shfl_xor(sq, off, 64);
    }
    const float mean = s * (1.f / CDIM);
    const float var  = sq * (1.f / CDIM) - mean * mean;
    const float rstd = rsqrtf(var + 1e-5f);
    u16* orow = outw + (size_t)t * CDIM;
#pragma unroll
    for (int i = 0; i < 6; i++) {
        const int c = lane + 64 * i;
        orow[c] = f2bf((v[i] - mean) * rstd * g[c] + b[c]);
    }
}

// ---------------- LN2 (straight rows, fp32 input, bf16 out) ----------------
__global__ __launch_bounds__(256) void k_ln2(const float* __restrict__ y,
    const float* __restrict__ g, const float* __restrict__ b, u16* __restrict__ outw)
{
    const int lane = threadIdx.x & 63;
    const int t = blockIdx.x * 4 + (threadIdx.x >> 6);
    const float* row = y + (size_t)t * CDIM;
    float v[6]; float s = 0.f, sq = 0.f;
#pragma unroll
    for (int i = 0; i < 6; i++) {
        v[i] = row[lane + 64 * i];
        s += v[i]; sq += v[i] * v[i];
    }
#pragma unroll
    for (int off = 32; off >= 1; off >>= 1) {
        s  += __shfl_xor(s, off, 64);
        sq += __shfl_xor(sq, off, 64);
    }
    const float mean = s * (1.f / CDIM);
    const float var  = sq * (1.f / CDIM) - mean * mean;
    const float rstd = rsqrtf(var + 1e-5f);
    u16* orow = outw + (size_t)t * CDIM;
#pragma unroll
    for (int i = 0; i < 6; i++) {
        const int c = lane + 64 * i;
        orow[c] = f2bf((v[i] - mean) * rstd * g[c] + b[c]);
    }
}

// ---------------- generic tiled GEMM: C = A_bf16(MxK) * B_f32(KxN) + bias ----------
// MODE 0: qkv  -> scatter to q/k/v [part][Bn][NH][49][32] (bf16), q pre-scaled
// MODE 1: proj -> window-reverse + roll(+3) scatter; Y = x_residual + val (fp32 out)
// MODE 2: fc1  -> exact GELU, bf16 row-major out
// MODE 3: fc2  -> + Y residual (fp32), fp32 out to d_out
template<int MODE>
__global__ __launch_bounds__(256) void k_gemm(
    const u16* __restrict__ A, const float* __restrict__ B,
    const float* __restrict__ bias,
    u16* __restrict__ out_bf,
    const float* __restrict__ res_f,
    float* __restrict__ out_f,
    int M, int Nn, int K)
{
    __shared__ float As[16][68];   // [k][m], padded; rows 272B = 17*16B aligned
    __shared__ float Bs[16][68];   // [k][n]
    const int tid = threadIdx.x;
    const int tx = tid & 15, ty = tid >> 4;
    const int m0 = blockIdx.x * 64, n0 = blockIdx.y * 64;
    const int la_m = tid >> 2, la_k4 = (tid & 3) << 2;
    const int lb_k = tid >> 4, lb_n4 = (tid & 15) << 2;
    const u16* Ap = A + (size_t)(m0 + la_m) * K + la_k4;
    const float* Bp = B + (size_t)lb_k * Nn + (n0 + lb_n4);
    float acc[4][4] = {{0.f}};
    ushort4 a4 = *(const ushort4*)Ap;
    float4 b4 = *(const float4*)Bp;
    for (int k0 = 0; k0 < K; k0 += 16) {
        As[la_k4 + 0][la_m] = bf2f(a4.x);
        As[la_k4 + 1][la_m] = bf2f(a4.y);
        As[la_k4 + 2][la_m] = bf2f(a4.z);
        As[la_k4 + 3][la_m] = bf2f(a4.w);
        *(float4*)&Bs[lb_k][lb_n4] = b4;
        __syncthreads();
        const int kn = (k0 + 16 < K) ? (k0 + 16) : k0;   // harmless re-read on last tile
        a4 = *(const ushort4*)(Ap + kn);
        b4 = *(const float4*)(Bp + (size_t)kn * Nn);
#pragma unroll
        for (int k = 0; k < 16; k++) {
            const float4 av = *(const float4*)&As[k][ty << 2];
            const float4 bv = *(const float4*)&Bs[k][tx << 2];
            acc[0][0] += av.x * bv.x; acc[0][1] += av.x * bv.y; acc[0][2] += av.x * bv.z; acc[0][3] += av.x * bv.w;
            acc[1][0] += av.y * bv.x; acc[1][1] += av.y * bv.y; acc[1][2] += av.y * bv.z; acc[1][3] += av.y * bv.w;
            acc[2][0] += av.z * bv.x; acc[2][1] += av.z * bv.y; acc[2][2] += av.z * bv.z; acc[2][3] += av.z * bv.w;
            acc[3][0] += av.w * bv.x; acc[3][1] += av.w * bv.y; acc[3][2] += av.w * bv.z; acc[3][3] += av.w * bv.w;
        }
        __syncthreads();
    }

#pragma unroll
    for (int i = 0; i < 4; i++) {
        const int m = m0 + (ty << 2) + i;
        if constexpr (MODE == 0) {
            const int wi = m / NTOK, n = m % NTOK;
#pragma unroll
            for (int j = 0; j < 4; j++) {
                const int col = n0 + (tx << 2) + j;
                float val = acc[i][j] + bias[col];
                const int part = col / CDIM;
                const int hcol = (col % CDIM) >> 5;
                const int d = col & 31;
                if (part == 0) val *= ATT_SCALE;
                out_bf[(size_t)part * QKV_STRIDE +
                       (((size_t)wi * NHEADS + hcol) * NTOK + n) * HDIM + d] = f2bf(val);
            }
        } else if constexpr (MODE == 1) {
            const int wi = m / NTOK, n = m % NTOK;
            const int bb = wi >> 6, w64 = wi & 63;
            const int p = (w64 >> 3) * 7 + n / 7;
            const int q = (w64 & 7) * 7 + n % 7;
            const int sh = (p + 3) % 56, sw = (q + 3) % 56;  // roll back by +3
            const size_t drow = ((size_t)bb * 3136 + sh * 56 + sw) * CDIM;
#pragma unroll
            for (int j = 0; j < 4; j++) {
                const int col = n0 + (tx << 2) + j;
                const float val = acc[i][j] + bias[col];
                out_f[drow + col] = res_f[drow + col] + val;
            }
        } else if constexpr (MODE == 2) {
#pragma unroll
            for (int j = 0; j < 4; j++) {
                const int col = n0 + (tx << 2) + j;
                const float v = acc[i][j] + bias[col];
                const float gel = 0.5f * v * (1.0f + erff(v * 0.70710678118654752f));
                out_bf[(size_t)m * HIDDIM + col] = f2bf(gel);
            }
        } else {  // MODE 3
#pragma unroll
            for (int j = 0; j < 4; j++) {
                const int col = n0 + (tx << 2) + j;
                out_f[(size_t)m * CDIM + col] =
                    acc[i][j] + bias[col] + res_f[(size_t)m * CDIM + col];
            }
        }
    }
}

// ---------------- windowed attention: one wave per (window, head) ----------------
__global__ __launch_bounds__(64) void k_attn(
    const u16* __restrict__ qkv, const float* __restrict__ rpb,
    const float* __restrict__ amask, u16* __restrict__ ctx)
{
    __shared__ __align__(16) float ks[NTOK * HDIM];
    __shared__ __align__(16) float vs[NTOK * HDIM];
    const int wi = blockIdx.x / NHEADS;
    const int h  = blockIdx.x % NHEADS;
    const int tid = threadIdx.x;
    const u16* qb = qkv + ((size_t)wi * NHEADS + h) * (NTOK * HDIM);
    const u16* kb = qb + QKV_STRIDE;
    const u16* vb = qb + 2 * QKV_STRIDE;
    for (int i = tid; i < NTOK * HDIM; i += 64) {
        ks[i] = bf2f(kb[i]);
        vs[i] = bf2f(vb[i]);
    }
    __syncthreads();
    const int n = tid;
    if (n < NTOK) {
        float qr[HDIM];
        const ushort4* q4 = (const ushort4*)(qb + n * HDIM);
#pragma unroll
        for (int d4 = 0; d4 < 8; d4++) {
            const ushort4 t = q4[d4];
            qr[4 * d4 + 0] = bf2f(t.x); qr[4 * d4 + 1] = bf2f(t.y);
            qr[4 * d4 + 2] = bf2f(t.z); qr[4 * d4 + 3] = bf2f(t.w);
        }
        const int in7 = n / 7, jn7 = n % 7;
        const float* mrow = amask + ((size_t)(wi & 63) * NTOK + n) * NTOK;
        float s[NTOK];
        float mx = -1e30f;
        for (int m = 0; m < NTOK; m++) {
            const float4* kk = (const float4*)&ks[m * HDIM];
            float a = 0.f;
#pragma unroll
            for (int d4 = 0; d4 < 8; d4++) {
                const float4 kv = kk[d4];
                a += qr[4 * d4 + 0] * kv.x + qr[4 * d4 + 1] * kv.y
                   + qr[4 * d4 + 2] * kv.z + qr[4 * d4 + 3] * kv.w;
            }
            const int ridx = (in7 - m / 7 + 6) * 13 + (jn7 - m % 7 + 6);
            a += rpb[ridx * NHEADS + h] + mrow[m];
            s[m] = a;
            mx = fmaxf(mx, a);
        }
        float ssum = 0.f;
        for (int m = 0; m < NTOK; m++) { const float e = __expf(s[m] - mx); s[m] = e; ssum += e; }
        const float inv = 1.f / ssum;
        float o[HDIM];
#pragma unroll
        for (int d = 0; d < HDIM; d++) o[d] = 0.f;
        for (int m = 0; m < NTOK; m++) {
            const float pm = s[m] * inv;
            const float4* vv = (const float4*)&vs[m * HDIM];
#pragma unroll
            for (int d4 = 0; d4 < 8; d4++) {
                const float4 v4 = vv[d4];
                o[4 * d4 + 0] += pm * v4.x; o[4 * d4 + 1] += pm * v4.y;
                o[4 * d4 + 2] += pm * v4.z; o[4 * d4 + 3] += pm * v4.w;
            }
        }
        u16* orow = ctx + ((size_t)wi * NTOK + n) * CDIM + h * HDIM;
#pragma unroll
        for (int d = 0; d < HDIM; d++) orow[d] = f2bf(o[d]);
    }
}

extern "C" void kernel_launch(void* const* d_in, const int* in_sizes, int n_in,
                              void* d_out, int out_size, void* d_ws, size_t ws_size,
                              hipStream_t stream)
{
    (void)in_sizes; (void)n_in; (void)out_size; (void)ws_size;
    const float* x     = (const float*)d_in[0];
    const float* amask = (const float*)d_in[1];
    const float* n1g   = (const float*)d_in[2];
    const float* n1b   = (const float*)d_in[3];
    const float* qkvw  = (const float*)d_in[4];
    const float* qkvb  = (const float*)d_in[5];
    const float* rpb   = (const float*)d_in[6];
    const float* projw = (const float*)d_in[7];
    const float* projb = (const float*)d_in[8];
    const float* n2g   = (const float*)d_in[9];
    const float* n2b   = (const float*)d_in[10];
    const float* fc1w  = (const float*)d_in[11];
    const float* fc1b  = (const float*)d_in[12];
    const float* fc2w  = (const float*)d_in[13];
    const float* fc2b  = (const float*)d_in[14];
    float* out = (float*)d_out;

    // workspace layout (total 539,492,352 B — same extent as round 1, which ran
    // without fault):
    //   [A: 77MB bf16 win-LN rows][QKV: 231MB bf16][Ctx: 77MB bf16][Y: 154MB fp32]
    //   H2 reuses A; FC1-mid (308MB bf16) reuses QKV+Ctx exactly.
    char* ws = (char*)d_ws;
    const size_t szA   = (size_t)MROWS * CDIM * 2;   // 77,070,336
    const size_t szQKV = 3 * szA;                    // 231,211,008
    u16*   Abuf = (u16*)ws;
    u16*   QKV  = (u16*)(ws + szA);
    u16*   Ctx  = (u16*)(ws + szA + szQKV);
    float* Y    = (float*)(ws + szA + szQKV + szA);
    u16*   H2   = Abuf;
    u16*   Mid  = QKV;

    k_ln1<<<MROWS / 4, 256, 0, stream>>>(x, n1g, n1b, Abuf);
    {
        dim3 g(MROWS / 64, 1152 / 64);
        k_gemm<0><<<g, 256, 0, stream>>>(Abuf, qkvw, qkvb, QKV, nullptr, nullptr, MROWS, 1152, CDIM);
    }
    k_attn<<<BNWIN * NHEADS, 64, 0, stream>>>(QKV, rpb, amask, Ctx);
    {
        dim3 g(MROWS / 64, CDIM / 64);
        k_gemm<1><<<g, 256, 0, stream>>>(Ctx, projw, projb, nullptr, x, Y, MROWS, CDIM, CDIM);
    }
    k_ln2<<<MROWS / 4, 256, 0, stream>>>(Y, n2g, n2b, H2);
    {
        dim3 g(MROWS / 64, HIDDIM / 64);
        k_gemm<2><<<g, 256, 0, stream>>>(H2, fc1w, fc1b, Mid, nullptr, nullptr, MROWS, HIDDIM, CDIM);
    }
    {
        dim3 g(MROWS / 64, CDIM / 64);
        k_gemm<3><<<g, 256, 0, stream>>>(Mid, fc2w, fc2b, nullptr, Y, out, MROWS, CDIM, HIDDIM);
    }
}

// Round 3
// 1791.343 us; speedup vs baseline: 2.8909x; 2.8909x over previous
//
#include <hip/hip_runtime.h>
#include <stdint.h>
#include <math.h>

typedef unsigned short u16;
using short8 = __attribute__((ext_vector_type(8))) short;
using f32x4  = __attribute__((ext_vector_type(4))) float;

#define NHEADS 12
#define NTOK 49
#define CDIM 384
#define HIDDIM 1536
#define HDIM 32
#define BNWIN 2048                 // 32 batches * 64 windows
#define MROWS 100352               // BNWIN * NTOK
#define QKV_STRIDE ((size_t)BNWIN * NHEADS * NTOK * HDIM)   // 38535168 elems
#define ATT_SCALE 0.17677669529663687f

__device__ __forceinline__ float bf2f(u16 u) {
    union { unsigned int i; float f; } z; z.i = ((unsigned int)u) << 16; return z.f;
}
__device__ __forceinline__ u16 f2bf(float f) {
    union { float f; unsigned int i; } z; z.f = f;
    unsigned int i = z.i;
    i += 0x7FFFu + ((i >> 16) & 1u);   // round-to-nearest-even
    return (u16)(i >> 16);
}

__device__ __forceinline__ void async16(const void* g, void* l) {
    __builtin_amdgcn_global_load_lds(
        (const __attribute__((address_space(1))) void*)g,
        (__attribute__((address_space(3))) void*)l, 16, 0, 0);
}

// ---------------- weight convert+transpose: B_f32[K][N] -> BT_bf16[N][K] -------
__global__ __launch_bounds__(256) void k_conv(const float* __restrict__ B,
    u16* __restrict__ BT, int K, int N)
{
    const int idx = blockIdx.x * 256 + threadIdx.x;
    if (idx >= K * N) return;
    const int n = idx / K, k = idx - n * K;
    BT[idx] = f2bf(B[(size_t)k * N + n]);
}

// ---------------- LN1 + roll(-3,-3) + window partition (gather) ----------------
__global__ __launch_bounds__(256) void k_ln1(const float* __restrict__ x,
    const float* __restrict__ g, const float* __restrict__ b, u16* __restrict__ outw)
{
    const int lane = threadIdx.x & 63;
    const int t = blockIdx.x * 4 + (threadIdx.x >> 6);     // 0..100351
    const int wi = t / NTOK, n = t % NTOK;
    const int bb = wi >> 6, w64 = wi & 63;
    const int p = (w64 >> 3) * 7 + n / 7;
    const int q = (w64 & 7) * 7 + n % 7;
    const int sh = (p + 3) % 56, sw = (q + 3) % 56;        // roll by -3
    const float* row = x + ((size_t)bb * 3136 + sh * 56 + sw) * CDIM;
    float v[6]; float s = 0.f, sq = 0.f;
#pragma unroll
    for (int i = 0; i < 6; i++) {
        v[i] = row[lane + 64 * i];
        s += v[i]; sq += v[i] * v[i];
    }
#pragma unroll
    for (int off = 32; off >= 1; off >>= 1) {
        s  += __shfl_xor(s, off, 64);
        sq += __shfl_xor(sq, off, 64);
    }
    const float mean = s * (1.f / CDIM);
    const float var  = sq * (1.f / CDIM) - mean * mean;
    const float rstd = rsqrtf(var + 1e-5f);
    u16* orow = outw + (size_t)t * CDIM;
#pragma unroll
    for (int i = 0; i < 6; i++) {
        const int c = lane + 64 * i;
        orow[c] = f2bf((v[i] - mean) * rstd * g[c] + b[c]);
    }
}

// ---------------- LN2 (straight rows, fp32 input from d_out, bf16 out) ---------
__global__ __launch_bounds__(256) void k_ln2(const float* __restrict__ y,
    const float* __restrict__ g, const float* __restrict__ b, u16* __restrict__ outw)
{
    const int lane = threadIdx.x & 63;
    const int t = blockIdx.x * 4 + (threadIdx.x >> 6);
    const float* row = y + (size_t)t * CDIM;
    float v[6]; float s = 0.f, sq = 0.f;
#pragma unroll
    for (int i = 0; i < 6; i++) {
        v[i] = row[lane + 64 * i];
        s += v[i]; sq += v[i] * v[i];
    }
#pragma unroll
    for (int off = 32; off >= 1; off >>= 1) {
        s  += __shfl_xor(s, off, 64);
        sq += __shfl_xor(sq, off, 64);
    }
    const float mean = s * (1.f / CDIM);
    const float var  = sq * (1.f / CDIM) - mean * mean;
    const float rstd = rsqrtf(var + 1e-5f);
    u16* orow = outw + (size_t)t * CDIM;
#pragma unroll
    for (int i = 0; i < 6; i++) {
        const int c = lane + 64 * i;
        orow[c] = f2bf((v[i] - mean) * rstd * g[c] + b[c]);
    }
}

// ---------------- MFMA GEMM: C = A_bf16(MxK) * BT_bf16(N x K)^T + bias ---------
// 128x128 tile, BK=32, 4 waves in 2x2, each wave 4x4 accs of 16x16x32 MFMA.
// XOR-swizzled LDS k-chunks: lds seg (row,q) holds global chunk q^((row>>1)&3).
// MODE 0: qkv  -> scatter q/k/v [part][Bn][NH][49][32] (bf16), q pre-scaled
// MODE 1: proj -> window-reverse + roll(+3); out_f = res_f + val (Y into d_out)
// MODE 2: fc1  -> exact GELU, bf16 row-major out
// MODE 3: fc2  -> out_f = val + bias + res_f (in-place on d_out, one touch/elem)
template<int MODE>
__global__ __launch_bounds__(256) void k_mgemm(
    const u16* __restrict__ A, const u16* __restrict__ BT,
    const float* __restrict__ bias,
    u16* __restrict__ out_bf,
    const float* res_f,
    float* out_f,
    int M, int Nn, int K)
{
    __shared__ __align__(16) u16 Als[128 * 32];
    __shared__ __align__(16) u16 Bls[128 * 32];
    const int tid = threadIdx.x;
    const int w = tid >> 6, l = tid & 63;
    const int wr = w >> 1, wc = w & 1;
    const int lrow = l & 15, quad = l >> 4;
    const int m0 = blockIdx.x * 128, n0 = blockIdx.y * 128;

    // staging: 512 16B segments per matrix, 2 per thread
    const int seg0 = tid, seg1 = tid + 256;
    const int r0 = seg0 >> 2, q0 = (seg0 & 3) ^ ((r0 >> 1) & 3);
    const int r1 = seg1 >> 2, q1 = (seg1 & 3) ^ ((r1 >> 1) & 3);
    const u16* Ag0 = A  + (size_t)(m0 + r0) * K + q0 * 8;
    const u16* Ag1 = A  + (size_t)(m0 + r1) * K + q1 * 8;
    const u16* Bg0 = BT + (size_t)(n0 + r0) * K + q0 * 8;
    const u16* Bg1 = BT + (size_t)(n0 + r1) * K + q1 * 8;
    u16* Al0 = &Als[seg0 * 8]; u16* Al1 = &Als[seg1 * 8];
    u16* Bl0 = &Bls[seg0 * 8]; u16* Bl1 = &Bls[seg1 * 8];

    // fragment LDS pointers (constant across K-loop)
    const short8* afp[4]; const short8* bfp[4];
#pragma unroll
    for (int i = 0; i < 4; i++) {
        const int ra = wr * 64 + i * 16 + lrow;
        afp[i] = (const short8*)&Als[ra * 32 + ((quad ^ ((ra >> 1) & 3)) << 3)];
        const int rb = wc * 64 + i * 16 + lrow;
        bfp[i] = (const short8*)&Bls[rb * 32 + ((quad ^ ((rb >> 1) & 3)) << 3)];
    }

    f32x4 acc[4][4];
#pragma unroll
    for (int i = 0; i < 4; i++)
#pragma unroll
        for (int j = 0; j < 4; j++)
            acc[i][j] = (f32x4){0.f, 0.f, 0.f, 0.f};

    for (int k0 = 0; k0 < K; k0 += 32) {
        async16(Ag0 + k0, Al0);
        async16(Ag1 + k0, Al1);
        async16(Bg0 + k0, Bl0);
        async16(Bg1 + k0, Bl1);
        __syncthreads();
        short8 af[4], bf[4];
#pragma unroll
        for (int i = 0; i < 4; i++) { af[i] = *afp[i]; bf[i] = *bfp[i]; }
#pragma unroll
        for (int mi = 0; mi < 4; mi++)
#pragma unroll
            for (int ni = 0; ni < 4; ni++)
                acc[mi][ni] = __builtin_amdgcn_mfma_f32_16x16x32_bf16(
                    af[mi], bf[ni], acc[mi][ni], 0, 0, 0);
        __syncthreads();
    }

    // epilogue: C[row=quad*4+r (+16*mi +64*wr), col=lrow (+16*ni +64*wc)]
    const int mbase = m0 + wr * 64 + quad * 4;
    const int nbase = n0 + wc * 64 + lrow;
#pragma unroll
    for (int mi = 0; mi < 4; mi++) {
#pragma unroll
        for (int r = 0; r < 4; r++) {
            const int grow = mbase + mi * 16 + r;
            if constexpr (MODE == 0) {
                const int wi = grow / NTOK, n = grow % NTOK;
#pragma unroll
                for (int ni = 0; ni < 4; ni++) {
                    const int gcol = nbase + ni * 16;
                    float val = acc[mi][ni][r] + bias[gcol];
                    const int part = gcol / CDIM;
                    const int rem = gcol % CDIM;
                    const int hcol = rem >> 5, d = rem & 31;
                    if (part == 0) val *= ATT_SCALE;
                    out_bf[(size_t)part * QKV_STRIDE +
                           (((size_t)wi * NHEADS + hcol) * NTOK + n) * HDIM + d] = f2bf(val);
                }
            } else if constexpr (MODE == 1) {
                const int wi = grow / NTOK, n = grow % NTOK;
                const int bb = wi >> 6, w64 = wi & 63;
                const int p = (w64 >> 3) * 7 + n / 7;
                const int q = (w64 & 7) * 7 + n % 7;
                const int sh = (p + 3) % 56, sw = (q + 3) % 56;
                const size_t drow = ((size_t)bb * 3136 + sh * 56 + sw) * CDIM;
#pragma unroll
                for (int ni = 0; ni < 4; ni++) {
                    const int gcol = nbase + ni * 16;
                    out_f[drow + gcol] = res_f[drow + gcol] + acc[mi][ni][r] + bias[gcol];
                }
            } else if constexpr (MODE == 2) {
#pragma unroll
                for (int ni = 0; ni < 4; ni++) {
                    const int gcol = nbase + ni * 16;
                    const float v = acc[mi][ni][r] + bias[gcol];
                    const float gel = 0.5f * v * (1.0f + erff(v * 0.70710678118654752f));
                    out_bf[(size_t)grow * Nn + gcol] = f2bf(gel);
                }
            } else {  // MODE 3
#pragma unroll
                for (int ni = 0; ni < 4; ni++) {
                    const int gcol = nbase + ni * 16;
                    const size_t o = (size_t)grow * Nn + gcol;
                    out_f[o] = acc[mi][ni][r] + bias[gcol] + res_f[o];
                }
            }
        }
    }
}

// ---------------- windowed attention: one wave per (window, head) ----------------
__global__ __launch_bounds__(64) void k_attn(
    const u16* __restrict__ qkv, const float* __restrict__ rpb,
    const float* __restrict__ amask, u16* __restrict__ ctx)
{
    __shared__ __align__(16) float ks[NTOK * HDIM];
    __shared__ __align__(16) float vs[NTOK * HDIM];
    const int wi = blockIdx.x / NHEADS;
    const int h  = blockIdx.x % NHEADS;
    const int tid = threadIdx.x;
    const u16* qb = qkv + ((size_t)wi * NHEADS + h) * (NTOK * HDIM);
    const u16* kb = qb + QKV_STRIDE;
    const u16* vb = qb + 2 * QKV_STRIDE;
    for (int i = tid; i < NTOK * HDIM; i += 64) {
        ks[i] = bf2f(kb[i]);
        vs[i] = bf2f(vb[i]);
    }
    __syncthreads();
    const int n = tid;
    if (n < NTOK) {
        float qr[HDIM];
        const ushort4* q4 = (const ushort4*)(qb + n * HDIM);
#pragma unroll
        for (int d4 = 0; d4 < 8; d4++) {
            const ushort4 t = q4[d4];
            qr[4 * d4 + 0] = bf2f(t.x); qr[4 * d4 + 1] = bf2f(t.y);
            qr[4 * d4 + 2] = bf2f(t.z); qr[4 * d4 + 3] = bf2f(t.w);
        }
        const int in7 = n / 7, jn7 = n % 7;
        const float* mrow = amask + ((size_t)(wi & 63) * NTOK + n) * NTOK;
        float s[NTOK];
        float mx = -1e30f;
        for (int m = 0; m < NTOK; m++) {
            const float4* kk = (const float4*)&ks[m * HDIM];
            float a = 0.f;
#pragma unroll
            for (int d4 = 0; d4 < 8; d4++) {
                const float4 kv = kk[d4];
                a += qr[4 * d4 + 0] * kv.x + qr[4 * d4 + 1] * kv.y
                   + qr[4 * d4 + 2] * kv.z + qr[4 * d4 + 3] * kv.w;
            }
            const int ridx = (in7 - m / 7 + 6) * 13 + (jn7 - m % 7 + 6);
            a += rpb[ridx * NHEADS + h] + mrow[m];
            s[m] = a;
            mx = fmaxf(mx, a);
        }
        float ssum = 0.f;
        for (int m = 0; m < NTOK; m++) { const float e = __expf(s[m] - mx); s[m] = e; ssum += e; }
        const float inv = 1.f / ssum;
        float o[HDIM];
#pragma unroll
        for (int d = 0; d < HDIM; d++) o[d] = 0.f;
        for (int m = 0; m < NTOK; m++) {
            const float pm = s[m] * inv;
            const float4* vv = (const float4*)&vs[m * HDIM];
#pragma unroll
            for (int d4 = 0; d4 < 8; d4++) {
                const float4 v4 = vv[d4];
                o[4 * d4 + 0] += pm * v4.x; o[4 * d4 + 1] += pm * v4.y;
                o[4 * d4 + 2] += pm * v4.z; o[4 * d4 + 3] += pm * v4.w;
            }
        }
        u16* orow = ctx + ((size_t)wi * NTOK + n) * CDIM + h * HDIM;
#pragma unroll
        for (int d = 0; d < HDIM; d++) orow[d] = f2bf(o[d]);
    }
}

extern "C" void kernel_launch(void* const* d_in, const int* in_sizes, int n_in,
                              void* d_out, int out_size, void* d_ws, size_t ws_size,
                              hipStream_t stream)
{
    (void)in_sizes; (void)n_in; (void)out_size; (void)ws_size;
    const float* x     = (const float*)d_in[0];
    const float* amask = (const float*)d_in[1];
    const float* n1g   = (const float*)d_in[2];
    const float* n1b   = (const float*)d_in[3];
    const float* qkvw  = (const float*)d_in[4];
    const float* qkvb  = (const float*)d_in[5];
    const float* rpb   = (const float*)d_in[6];
    const float* projw = (const float*)d_in[7];
    const float* projb = (const float*)d_in[8];
    const float* n2g   = (const float*)d_in[9];
    const float* n2b   = (const float*)d_in[10];
    const float* fc1w  = (const float*)d_in[11];
    const float* fc1b  = (const float*)d_in[12];
    const float* fc2w  = (const float*)d_in[13];
    const float* fc2b  = (const float*)d_in[14];
    float* out = (float*)d_out;   // doubles as Y (x + attn residual) scratch

    // workspace layout (388.9 MB used, < 539.5 MB proven extent):
    //   [A 77MB bf16][QKV 231MB bf16][Ctx 77MB bf16][BT weights 3.5MB bf16]
    //   H2 reuses A; FC1-mid (308MB bf16) reuses QKV+Ctx exactly; Y lives in d_out.
    char* ws = (char*)d_ws;
    const size_t szA   = (size_t)MROWS * CDIM * 2;   // 77,070,336
    const size_t szQKV = 3 * szA;                    // 231,211,008
    u16*   Abuf = (u16*)ws;
    u16*   QKV  = (u16*)(ws + szA);
    u16*   Ctx  = (u16*)(ws + szA + szQKV);
    u16*   qkvT = (u16*)(ws + szA + szQKV + szA);
    u16*   projT = qkvT + 1152 * 384;
    u16*   fc1T  = projT + 384 * 384;
    u16*   fc2T  = fc1T + 1536 * 384;
    u16*   H2   = Abuf;
    u16*   Mid  = QKV;

    // weight convert+transpose (bf16 [N][K])
    k_conv<<<(384 * 1152 + 255) / 256, 256, 0, stream>>>(qkvw, qkvT, 384, 1152);
    k_conv<<<(384 * 384 + 255) / 256, 256, 0, stream>>>(projw, projT, 384, 384);
    k_conv<<<(384 * 1536 + 255) / 256, 256, 0, stream>>>(fc1w, fc1T, 384, 1536);
    k_conv<<<(1536 * 384 + 255) / 256, 256, 0, stream>>>(fc2w, fc2T, 1536, 384);

    k_ln1<<<MROWS / 4, 256, 0, stream>>>(x, n1g, n1b, Abuf);
    {
        dim3 g(MROWS / 128, 1152 / 128);
        k_mgemm<0><<<g, 256, 0, stream>>>(Abuf, qkvT, qkvb, QKV, nullptr, nullptr, MROWS, 1152, 384);
    }
    k_attn<<<BNWIN * NHEADS, 64, 0, stream>>>(QKV, rpb, amask, Ctx);
    {
        dim3 g(MROWS / 128, 384 / 128);
        k_mgemm<1><<<g, 256, 0, stream>>>(Ctx, projT, projb, nullptr, x, out, MROWS, 384, 384);
    }
    k_ln2<<<MROWS / 4, 256, 0, stream>>>(out, n2g, n2b, H2);
    {
        dim3 g(MROWS / 128, 1536 / 128);
        k_mgemm<2><<<g, 256, 0, stream>>>(H2, fc1T, fc1b, Mid, nullptr, nullptr, MROWS, 1536, 384);
    }
    {
        dim3 g(MROWS / 128, 384 / 128);
        k_mgemm<3><<<g, 256, 0, stream>>>(Mid, fc2T, fc2b, nullptr, out, out, MROWS, 384, 1536);
    }
}

// Round 4
// 1717.245 us; speedup vs baseline: 3.0156x; 1.0431x over previous
//
#include <hip/hip_runtime.h>
#include <stdint.h>
#include <math.h>

typedef unsigned short u16;
typedef unsigned int u32;
using short8 = __attribute__((ext_vector_type(8))) short;
using f32x4  = __attribute__((ext_vector_type(4))) float;

#define NHEADS 12
#define NTOK 49
#define CDIM 384
#define HIDDIM 1536
#define HDIM 32
#define BNWIN 2048                 // 32 batches * 64 windows
#define MROWS 100352               // BNWIN * NTOK
#define QKV_STRIDE ((size_t)BNWIN * NHEADS * NTOK * HDIM)   // 38535168 elems
#define ATT_SCALE 0.17677669529663687f
#define ATTW 2                     // waves per attention block

__device__ __forceinline__ float bf2f(u16 u) {
    union { unsigned int i; float f; } z; z.i = ((unsigned int)u) << 16; return z.f;
}
__device__ __forceinline__ u16 f2bf(float f) {
    union { float f; unsigned int i; } z; z.f = f;
    unsigned int i = z.i;
    i += 0x7FFFu + ((i >> 16) & 1u);   // round-to-nearest-even
    return (u16)(i >> 16);
}
__device__ __forceinline__ float lo16(u32 u) {
    union { u32 i; float f; } z; z.i = u << 16; return z.f;
}
__device__ __forceinline__ float hi16(u32 u) {
    union { u32 i; float f; } z; z.i = u & 0xffff0000u; return z.f;
}

__device__ __forceinline__ void async16(const void* g, void* l) {
    __builtin_amdgcn_global_load_lds(
        (const __attribute__((address_space(1))) void*)g,
        (__attribute__((address_space(3))) void*)l, 16, 0, 0);
}

// ---------------- weight convert+transpose: B_f32[K][N] -> BT_bf16[N][K] -------
__global__ __launch_bounds__(256) void k_conv(const float* __restrict__ B,
    u16* __restrict__ BT, int K, int N)
{
    const int idx = blockIdx.x * 256 + threadIdx.x;
    if (idx >= K * N) return;
    const int n = idx / K, k = idx - n * K;
    BT[idx] = f2bf(B[(size_t)k * N + n]);
}

// ---------------- LN1 + roll(-3,-3) + window partition (gather) ----------------
__global__ __launch_bounds__(256) void k_ln1(const float* __restrict__ x,
    const float* __restrict__ g, const float* __restrict__ b, u16* __restrict__ outw)
{
    const int lane = threadIdx.x & 63;
    const int t = blockIdx.x * 4 + (threadIdx.x >> 6);     // 0..100351
    const int wi = t / NTOK, n = t % NTOK;
    const int bb = wi >> 6, w64 = wi & 63;
    const int p = (w64 >> 3) * 7 + n / 7;
    const int q = (w64 & 7) * 7 + n % 7;
    const int sh = (p + 3) % 56, sw = (q + 3) % 56;        // roll by -3
    const float* row = x + ((size_t)bb * 3136 + sh * 56 + sw) * CDIM;
    float v[6]; float s = 0.f, sq = 0.f;
#pragma unroll
    for (int i = 0; i < 6; i++) {
        v[i] = row[lane + 64 * i];
        s += v[i]; sq += v[i] * v[i];
    }
#pragma unroll
    for (int off = 32; off >= 1; off >>= 1) {
        s  += __shfl_xor(s, off, 64);
        sq += __shfl_xor(sq, off, 64);
    }
    const float mean = s * (1.f / CDIM);
    const float var  = sq * (1.f / CDIM) - mean * mean;
    const float rstd = rsqrtf(var + 1e-5f);
    u16* orow = outw + (size_t)t * CDIM;
#pragma unroll
    for (int i = 0; i < 6; i++) {
        const int c = lane + 64 * i;
        orow[c] = f2bf((v[i] - mean) * rstd * g[c] + b[c]);
    }
}

// ---------------- LN2 (straight rows, fp32 input from d_out, bf16 out) ---------
__global__ __launch_bounds__(256) void k_ln2(const float* __restrict__ y,
    const float* __restrict__ g, const float* __restrict__ b, u16* __restrict__ outw)
{
    const int lane = threadIdx.x & 63;
    const int t = blockIdx.x * 4 + (threadIdx.x >> 6);
    const float* row = y + (size_t)t * CDIM;
    float v[6]; float s = 0.f, sq = 0.f;
#pragma unroll
    for (int i = 0; i < 6; i++) {
        v[i] = row[lane + 64 * i];
        s += v[i]; sq += v[i] * v[i];
    }
#pragma unroll
    for (int off = 32; off >= 1; off >>= 1) {
        s  += __shfl_xor(s, off, 64);
        sq += __shfl_xor(sq, off, 64);
    }
    const float mean = s * (1.f / CDIM);
    const float var  = sq * (1.f / CDIM) - mean * mean;
    const float rstd = rsqrtf(var + 1e-5f);
    u16* orow = outw + (size_t)t * CDIM;
#pragma unroll
    for (int i = 0; i < 6; i++) {
        const int c = lane + 64 * i;
        orow[c] = f2bf((v[i] - mean) * rstd * g[c] + b[c]);
    }
}

// ---------------- MFMA GEMM: C = A_bf16(MxK) * BT_bf16(N x K)^T + bias ---------
// (unchanged from round 3)
template<int MODE>
__global__ __launch_bounds__(256) void k_mgemm(
    const u16* __restrict__ A, const u16* __restrict__ BT,
    const float* __restrict__ bias,
    u16* __restrict__ out_bf,
    const float* res_f,
    float* out_f,
    int M, int Nn, int K)
{
    __shared__ __align__(16) u16 Als[128 * 32];
    __shared__ __align__(16) u16 Bls[128 * 32];
    const int tid = threadIdx.x;
    const int w = tid >> 6, l = tid & 63;
    const int wr = w >> 1, wc = w & 1;
    const int lrow = l & 15, quad = l >> 4;
    const int m0 = blockIdx.x * 128, n0 = blockIdx.y * 128;

    const int seg0 = tid, seg1 = tid + 256;
    const int r0 = seg0 >> 2, q0 = (seg0 & 3) ^ ((r0 >> 1) & 3);
    const int r1 = seg1 >> 2, q1 = (seg1 & 3) ^ ((r1 >> 1) & 3);
    const u16* Ag0 = A  + (size_t)(m0 + r0) * K + q0 * 8;
    const u16* Ag1 = A  + (size_t)(m0 + r1) * K + q1 * 8;
    const u16* Bg0 = BT + (size_t)(n0 + r0) * K + q0 * 8;
    const u16* Bg1 = BT + (size_t)(n0 + r1) * K + q1 * 8;
    u16* Al0 = &Als[seg0 * 8]; u16* Al1 = &Als[seg1 * 8];
    u16* Bl0 = &Bls[seg0 * 8]; u16* Bl1 = &Bls[seg1 * 8];

    const short8* afp[4]; const short8* bfp[4];
#pragma unroll
    for (int i = 0; i < 4; i++) {
        const int ra = wr * 64 + i * 16 + lrow;
        afp[i] = (const short8*)&Als[ra * 32 + ((quad ^ ((ra >> 1) & 3)) << 3)];
        const int rb = wc * 64 + i * 16 + lrow;
        bfp[i] = (const short8*)&Bls[rb * 32 + ((quad ^ ((rb >> 1) & 3)) << 3)];
    }

    f32x4 acc[4][4];
#pragma unroll
    for (int i = 0; i < 4; i++)
#pragma unroll
        for (int j = 0; j < 4; j++)
            acc[i][j] = (f32x4){0.f, 0.f, 0.f, 0.f};

    for (int k0 = 0; k0 < K; k0 += 32) {
        async16(Ag0 + k0, Al0);
        async16(Ag1 + k0, Al1);
        async16(Bg0 + k0, Bl0);
        async16(Bg1 + k0, Bl1);
        __syncthreads();
        short8 af[4], bf[4];
#pragma unroll
        for (int i = 0; i < 4; i++) { af[i] = *afp[i]; bf[i] = *bfp[i]; }
#pragma unroll
        for (int mi = 0; mi < 4; mi++)
#pragma unroll
            for (int ni = 0; ni < 4; ni++)
                acc[mi][ni] = __builtin_amdgcn_mfma_f32_16x16x32_bf16(
                    af[mi], bf[ni], acc[mi][ni], 0, 0, 0);
        __syncthreads();
    }

    const int mbase = m0 + wr * 64 + quad * 4;
    const int nbase = n0 + wc * 64 + lrow;
#pragma unroll
    for (int mi = 0; mi < 4; mi++) {
#pragma unroll
        for (int r = 0; r < 4; r++) {
            const int grow = mbase + mi * 16 + r;
            if constexpr (MODE == 0) {
                const int wi = grow / NTOK, n = grow % NTOK;
#pragma unroll
                for (int ni = 0; ni < 4; ni++) {
                    const int gcol = nbase + ni * 16;
                    float val = acc[mi][ni][r] + bias[gcol];
                    const int part = gcol / CDIM;
                    const int rem = gcol % CDIM;
                    const int hcol = rem >> 5, d = rem & 31;
                    if (part == 0) val *= ATT_SCALE;
                    out_bf[(size_t)part * QKV_STRIDE +
                           (((size_t)wi * NHEADS + hcol) * NTOK + n) * HDIM + d] = f2bf(val);
                }
            } else if constexpr (MODE == 1) {
                const int wi = grow / NTOK, n = grow % NTOK;
                const int bb = wi >> 6, w64 = wi & 63;
                const int p = (w64 >> 3) * 7 + n / 7;
                const int q = (w64 & 7) * 7 + n % 7;
                const int sh = (p + 3) % 56, sw = (q + 3) % 56;
                const size_t drow = ((size_t)bb * 3136 + sh * 56 + sw) * CDIM;
#pragma unroll
                for (int ni = 0; ni < 4; ni++) {
                    const int gcol = nbase + ni * 16;
                    out_f[drow + gcol] = res_f[drow + gcol] + acc[mi][ni][r] + bias[gcol];
                }
            } else if constexpr (MODE == 2) {
#pragma unroll
                for (int ni = 0; ni < 4; ni++) {
                    const int gcol = nbase + ni * 16;
                    const float v = acc[mi][ni][r] + bias[gcol];
                    const float gel = 0.5f * v * (1.0f + erff(v * 0.70710678118654752f));
                    out_bf[(size_t)grow * Nn + gcol] = f2bf(gel);
                }
            } else {  // MODE 3
#pragma unroll
                for (int ni = 0; ni < 4; ni++) {
                    const int gcol = nbase + ni * 16;
                    const size_t o = (size_t)grow * Nn + gcol;
                    out_f[o] = acc[mi][ni][r] + bias[gcol] + res_f[o];
                }
            }
        }
    }
}

// ---------------- windowed attention v2: no scratch spill, LDS score buffer ----
// One wave per (window, head); ATTW waves per block. Analytic Swin mask.
// LDS/wave: Kf,Vf f32 [49][32] + S f32 [49][51] (odd stride, conflict-free) + rpb slice.
__global__ __launch_bounds__(64 * ATTW) void k_attn(
    const u16* __restrict__ qkv, const float* __restrict__ rpb,
    u16* __restrict__ ctx)
{
    __shared__ __align__(16) float Kf[ATTW][NTOK * HDIM];
    __shared__ __align__(16) float Vf[ATTW][NTOK * HDIM];
    __shared__ float Sf[ATTW][NTOK * 51];
    __shared__ float rb[ATTW][170];

    const int wv = threadIdx.x >> 6, lane = threadIdx.x & 63;
    const int gwh = blockIdx.x * ATTW + wv;    // 0..24575
    const int wi = gwh / NHEADS, h = gwh % NHEADS;
    const u16* qb = qkv + (size_t)gwh * (NTOK * HDIM);
    const u16* kb = qb + QKV_STRIDE;
    const u16* vb = qb + 2 * QKV_STRIDE;

    // stage K,V -> LDS f32 (196 16B segs each), vectorized
    for (int i = lane; i < 196; i += 64) {
        const uint4 tk = ((const uint4*)kb)[i];
        const uint4 tv = ((const uint4*)vb)[i];
        float* kd = &Kf[wv][i * 8];
        float* vd = &Vf[wv][i * 8];
        *(float4*)kd       = make_float4(lo16(tk.x), hi16(tk.x), lo16(tk.y), hi16(tk.y));
        *(float4*)(kd + 4) = make_float4(lo16(tk.z), hi16(tk.z), lo16(tk.w), hi16(tk.w));
        *(float4*)vd       = make_float4(lo16(tv.x), hi16(tv.x), lo16(tv.y), hi16(tv.y));
        *(float4*)(vd + 4) = make_float4(lo16(tv.z), hi16(tv.z), lo16(tv.w), hi16(tv.w));
    }
    // stage rpb slice for this head
    for (int i = lane; i < 169; i += 64) rb[wv][i] = rpb[i * NHEADS + h];

    // per-lane query-side precompute (lane = query token n)
    const int n = lane;
    const int nc = (n < NTOK) ? n : 0;
    const int pn = nc / 7, qn = nc % 7;
    const int tcode = pn * 13 + qn;
    const int a = (wi & 63) >> 3, bwin = (wi & 63) & 7;
    const int rh = (a < 7) ? 0 : ((pn < 4) ? 1 : 2);
    const int rw = (bwin < 7) ? 0 : ((qn < 4) ? 1 : 2);
    const int reg = rh * 3 + rw;

    float qr[HDIM];
    if (n < NTOK) {
        const uint4* qp = (const uint4*)(qb + n * HDIM);
        uint4 qq[4];
#pragma unroll
        for (int i = 0; i < 4; i++) qq[i] = qp[i];
#pragma unroll
        for (int i = 0; i < 4; i++) {
            qr[i * 8 + 0] = lo16(qq[i].x); qr[i * 8 + 1] = hi16(qq[i].x);
            qr[i * 8 + 2] = lo16(qq[i].y); qr[i * 8 + 3] = hi16(qq[i].y);
            qr[i * 8 + 4] = lo16(qq[i].z); qr[i * 8 + 5] = hi16(qq[i].z);
            qr[i * 8 + 6] = lo16(qq[i].w); qr[i * 8 + 7] = hi16(qq[i].w);
        }
    }
    __syncthreads();

    if (n < NTOK) {
        const float* Kw = &Kf[wv][0];
        const float* Vw = &Vf[wv][0];
        float* Sr = &Sf[wv][n * 51];
        // phase 1: scores + row max
        float mx = -1e30f;
        for (int m = 0; m < NTOK; m++) {
            const float4* kr = (const float4*)(Kw + m * HDIM);
            float4 acc0 = make_float4(0.f, 0.f, 0.f, 0.f);
            float4 acc1 = make_float4(0.f, 0.f, 0.f, 0.f);
#pragma unroll
            for (int d4 = 0; d4 < 8; d4 += 2) {
                const float4 k0 = kr[d4], k1 = kr[d4 + 1];
                acc0.x += qr[d4 * 4 + 0] * k0.x; acc0.y += qr[d4 * 4 + 1] * k0.y;
                acc0.z += qr[d4 * 4 + 2] * k0.z; acc0.w += qr[d4 * 4 + 3] * k0.w;
                acc1.x += qr[d4 * 4 + 4] * k1.x; acc1.y += qr[d4 * 4 + 5] * k1.y;
                acc1.z += qr[d4 * 4 + 6] * k1.z; acc1.w += qr[d4 * 4 + 7] * k1.w;
            }
            float s = ((acc0.x + acc0.y) + (acc0.z + acc0.w))
                    + ((acc1.x + acc1.y) + (acc1.z + acc1.w));
            const int tm = __shfl(tcode, m);
            const int rm = __shfl(reg, m);
            s += rb[wv][tcode - tm + 84];
            s += (reg == rm) ? 0.f : -100.f;
            Sr[m] = s;
            mx = fmaxf(mx, s);
        }
        // phase 2: exp + PV accumulate (defer 1/l)
        float l = 0.f;
        float o[HDIM];
#pragma unroll
        for (int d = 0; d < HDIM; d++) o[d] = 0.f;
        for (int m = 0; m < NTOK; m++) {
            const float e = __expf(Sr[m] - mx);
            l += e;
            const float4* vr = (const float4*)(Vw + m * HDIM);
#pragma unroll
            for (int d4 = 0; d4 < 8; d4++) {
                const float4 v4 = vr[d4];
                o[d4 * 4 + 0] += e * v4.x; o[d4 * 4 + 1] += e * v4.y;
                o[d4 * 4 + 2] += e * v4.z; o[d4 * 4 + 3] += e * v4.w;
            }
        }
        const float inv = 1.f / l;
        u32 ow[16];
#pragma unroll
        for (int i = 0; i < 16; i++) {
            ow[i] = (u32)f2bf(o[2 * i] * inv) | ((u32)f2bf(o[2 * i + 1] * inv) << 16);
        }
        uint4* cp = (uint4*)(ctx + ((size_t)wi * NTOK + n) * CDIM + h * HDIM);
#pragma unroll
        for (int i = 0; i < 4; i++)
            cp[i] = make_uint4(ow[4 * i], ow[4 * i + 1], ow[4 * i + 2], ow[4 * i + 3]);
    }
}

extern "C" void kernel_launch(void* const* d_in, const int* in_sizes, int n_in,
                              void* d_out, int out_size, void* d_ws, size_t ws_size,
                              hipStream_t stream)
{
    (void)in_sizes; (void)n_in; (void)out_size; (void)ws_size;
    const float* x     = (const float*)d_in[0];
    const float* n1g   = (const float*)d_in[2];
    const float* n1b   = (const float*)d_in[3];
    const float* qkvw  = (const float*)d_in[4];
    const float* qkvb  = (const float*)d_in[5];
    const float* rpb   = (const float*)d_in[6];
    const float* projw = (const float*)d_in[7];
    const float* projb = (const float*)d_in[8];
    const float* n2g   = (const float*)d_in[9];
    const float* n2b   = (const float*)d_in[10];
    const float* fc1w  = (const float*)d_in[11];
    const float* fc1b  = (const float*)d_in[12];
    const float* fc2w  = (const float*)d_in[13];
    const float* fc2b  = (const float*)d_in[14];
    float* out = (float*)d_out;   // doubles as Y (x + attn residual) scratch

    char* ws = (char*)d_ws;
    const size_t szA   = (size_t)MROWS * CDIM * 2;   // 77,070,336
    const size_t szQKV = 3 * szA;                    // 231,211,008
    u16*   Abuf = (u16*)ws;
    u16*   QKV  = (u16*)(ws + szA);
    u16*   Ctx  = (u16*)(ws + szA + szQKV);
    u16*   qkvT = (u16*)(ws + szA + szQKV + szA);
    u16*   projT = qkvT + 1152 * 384;
    u16*   fc1T  = projT + 384 * 384;
    u16*   fc2T  = fc1T + 1536 * 384;
    u16*   H2   = Abuf;
    u16*   Mid  = QKV;

    k_conv<<<(384 * 1152 + 255) / 256, 256, 0, stream>>>(qkvw, qkvT, 384, 1152);
    k_conv<<<(384 * 384 + 255) / 256, 256, 0, stream>>>(projw, projT, 384, 384);
    k_conv<<<(384 * 1536 + 255) / 256, 256, 0, stream>>>(fc1w, fc1T, 384, 1536);
    k_conv<<<(1536 * 384 + 255) / 256, 256, 0, stream>>>(fc2w, fc2T, 1536, 384);

    k_ln1<<<MROWS / 4, 256, 0, stream>>>(x, n1g, n1b, Abuf);
    {
        dim3 g(MROWS / 128, 1152 / 128);
        k_mgemm<0><<<g, 256, 0, stream>>>(Abuf, qkvT, qkvb, QKV, nullptr, nullptr, MROWS, 1152, 384);
    }
    k_attn<<<(BNWIN * NHEADS) / ATTW, 64 * ATTW, 0, stream>>>(QKV, rpb, Ctx);
    {
        dim3 g(MROWS / 128, 384 / 128);
        k_mgemm<1><<<g, 256, 0, stream>>>(Ctx, projT, projb, nullptr, x, out, MROWS, 384, 384);
    }
    k_ln2<<<MROWS / 4, 256, 0, stream>>>(out, n2g, n2b, H2);
    {
        dim3 g(MROWS / 128, 1536 / 128);
        k_mgemm<2><<<g, 256, 0, stream>>>(H2, fc1T, fc1b, Mid, nullptr, nullptr, MROWS, 1536, 384);
    }
    {
        dim3 g(MROWS / 128, 384 / 128);
        k_mgemm<3><<<g, 256, 0, stream>>>(Mid, fc2T, fc2b, nullptr, out, out, MROWS, 384, 1536);
    }
}